// Round 4
// baseline (323.654 us; speedup 1.0000x reference)
//
#include <hip/hip_runtime.h>

// Problem constants
static constexpr int NN = 10000;   // nodes
static constexpr int DD = 64;      // in/out dim
static constexpr int KP = 10240;   // padded K for M_T
static constexpr int BK = 128;     // K per inner iter
static constexpr int SPLITS = 4;   // K-split factor (grid.y)
static constexpr int KC = KP / SPLITS;  // 2560 K per block
static constexpr int ITERS = KC / BK;   // 20
static constexpr int BM = 64;      // rows per block

typedef __attribute__((ext_vector_type(4))) float f32x4;
typedef __attribute__((ext_vector_type(8))) short s16x8;

__device__ __forceinline__ unsigned short f2bf(float f) {
  // fp32 -> bf16 round-to-nearest-even (bit trick; inputs finite)
  unsigned u = __float_as_uint(f);
  return (unsigned short)((u + 0x7fffu + ((u >> 16) & 1u)) >> 16);
}

// async global->LDS DMA, 16 B per lane: dest = ldsbase + lane*16 (wave-uniform base),
// src is per-lane (pre-swizzled global addressing, m173 pattern).
__device__ __forceinline__ void g2l16(const void* g, void* l) {
  __builtin_amdgcn_global_load_lds((const __attribute__((address_space(1))) unsigned int*)g,
                                   (__attribute__((address_space(3))) unsigned int*)l, 16, 0, 0);
}

// ---------- prep: M_T[r][d][k] = bf16( sum_j H[k][j] * W_r[d][j] ), zero-padded to KP ----------
__global__ void prep_kernel(const float* __restrict__ H,
                            const float* __restrict__ W1,
                            const float* __restrict__ W2,
                            const float* __restrict__ W3,
                            unsigned short* __restrict__ mt) {
  const int r = blockIdx.y;
  const float* W = (r == 0) ? W1 : (r == 1) ? W2 : W3;
  const int wave = threadIdx.x >> 6;
  const int lane = threadIdx.x & 63;   // lane == output dim d
  f32x4 wr[16];
#pragma unroll
  for (int i = 0; i < 16; ++i) wr[i] = *(const f32x4*)&W[lane * 64 + i * 4];
  unsigned short* orow = mt + ((size_t)r * 64 + lane) * KP;
  const int kbase = blockIdx.x * 128 + wave * 32;
  for (int i = 0; i < 32; ++i) {
    const int k = kbase + i;
    if (k < NN) {
      float s = 0.f;
#pragma unroll
      for (int j = 0; j < 16; ++j) {
        f32x4 h = *(const f32x4*)&H[(size_t)k * 64 + j * 4]; // wave-uniform addr -> broadcast
        s += h[0] * wr[j][0] + h[1] * wr[j][1] + h[2] * wr[j][2] + h[3] * wr[j][3];
      }
      orow[k] = f2bf(s);
    } else {
      orow[k] = 0;  // zero pad k in [10000,10240)
    }
  }
}

// ---------- init: out[v][d] = bias[d] ----------
__global__ void init_out_kernel(const float* __restrict__ bias, float* __restrict__ out) {
  const int i = blockIdx.x * 256 + threadIdx.x;
  if (i < NN * DD) out[i] = bias[i & 63];
}

// ---------- main: out += A_r[:, kchunk] @ M_r[kchunk, :]  (bf16 MFMA) ----------
// M staged via global_load_lds DMA (double-buffered; XOR seg-swizzle applied on the
// per-lane GLOBAL source and on the ds_read addr -> conflict-spread reads, linear dest).
// A double-buffered in registers. K split 4 ways (grid.y); partials via atomicAdd.
__global__ __launch_bounds__(256, 4) void gcn_main(const float* __restrict__ A1,
                                                   const float* __restrict__ A2,
                                                   const float* __restrict__ A3,
                                                   const unsigned short* __restrict__ mt,
                                                   float* __restrict__ out) {
  // [buf][row][128 hw]; row = 256 B = 16 segs of 16 B. Stored seg for (row, g) is
  // g ^ (row & 15) -- realized by pre-swizzling the DMA source, LDS dest stays linear.
  __shared__ __align__(1024) unsigned short mlds[2][64][128];

  const int r = blockIdx.z;
  const int s = blockIdx.y;
  const float* A = (r == 0) ? A1 : (r == 1) ? A2 : A3;
  const unsigned short* mtr = mt + (size_t)r * 64 * KP;

  const int wave = threadIdx.x >> 6;
  const int lane = threadIdx.x & 63;
  const int l15 = lane & 15;
  const int lhi = lane >> 4;
  const int seg = lane & 15;   // 16-B segment this lane DMAs
  const int r16 = lane >> 4;   // row-within-4 this lane DMAs
  const int v0 = blockIdx.x * BM;
  const int k0 = s * KC;

  // A row this lane streams (clamped for tail block; garbage rows never stored)
  int vA = v0 + wave * 16 + l15;
  if (vA > NN - 1) vA = NN - 1;
  const float* arow = A + (size_t)vA * NN;

  f32x4 acc[4] = {{0.f,0.f,0.f,0.f},{0.f,0.f,0.f,0.f},{0.f,0.f,0.f,0.f},{0.f,0.f,0.f,0.f}};
  f32x4 aF[4][2], aN[4][2];

  // DMA one BK-tile of M into mlds[buf]: wave w stages rows [16w,16w+16) as 4 ops.
  // Op j: lane l -> row 16w+4j+(l>>4), stored seg (l&15); source seg = (l&15)^(4j+(l>>4)).
  auto stageM = [&](int t, int buf) {
    const int kb = k0 + t * BK;
#pragma unroll
    for (int j = 0; j < 4; ++j) {
      const int row16 = 4 * j + r16;                 // row & 15
      const int rowabs = wave * 16 + row16;
      const unsigned short* src = mtr + (size_t)rowabs * KP + kb + ((seg ^ row16) << 3);
      g2l16(src, &mlds[buf][wave * 16 + 4 * j][0]);
    }
  };
  auto loadA = [&](f32x4 (&a)[4][2], int kb) {
    const bool guard = (kb + BK > NN);  // only final iters of last split
#pragma unroll
    for (int kk = 0; kk < 4; ++kk) {
      const int kf = kb + kk * 32 + lhi * 8;   // kf % 8 == 0, NN % 8 == 0
      if (!guard) {
        a[kk][0] = *(const f32x4*)(arow + kf);
        a[kk][1] = *(const f32x4*)(arow + kf + 4);
      } else {
        f32x4 z = {0.f, 0.f, 0.f, 0.f};
        if (kf < NN) {                          // kf<NN => kf+8<=NN (both mod 8)
          a[kk][0] = *(const f32x4*)(arow + kf);
          a[kk][1] = *(const f32x4*)(arow + kf + 4);
        } else {
          a[kk][0] = z; a[kk][1] = z;
        }
      }
    }
  };
  auto cvtA = [&](const f32x4& x, const f32x4& y) -> s16x8 {
    s16x8 v;
    v[0] = (short)f2bf(x[0]); v[1] = (short)f2bf(x[1]);
    v[2] = (short)f2bf(x[2]); v[3] = (short)f2bf(x[3]);
    v[4] = (short)f2bf(y[0]); v[5] = (short)f2bf(y[1]);
    v[6] = (short)f2bf(y[2]); v[7] = (short)f2bf(y[3]);
    return v;
  };

  // prologue: stage iter 0 (compiler's vmcnt(0)-drain at the barrier completes the DMA)
  stageM(0, 0);
  loadA(aF, k0);
  __syncthreads();

  for (int t = 0; t < ITERS; ++t) {
    const int buf = t & 1;
    const bool pref = (t + 1 < ITERS);
    if (pref) {
      loadA(aN, k0 + (t + 1) * BK);  // HBM prefetch into regs (kept live: 128-VGPR budget)
      stageM(t + 1, buf ^ 1);        // fire-and-forget DMA into the other buffer
    }
#pragma unroll
    for (int kk = 0; kk < 4; ++kk) {
      s16x8 a = cvtA(aF[kk][0], aF[kk][1]);
#pragma unroll
      for (int dt = 0; dt < 4; ++dt) {
        const int rrow = dt * 16 + l15;
        const int g = kk * 4 + lhi;
        s16x8 b = *(const s16x8*)&mlds[buf][rrow][((g ^ l15) & 15) * 8]; // rrow&15 == l15
        acc[dt] = __builtin_amdgcn_mfma_f32_16x16x32_bf16(a, b, acc[dt], 0, 0, 0);
      }
    }
    __syncthreads();   // drains DMA (vmcnt(0)) + guards buf reuse
    if (pref) {
#pragma unroll
      for (int kk = 0; kk < 4; ++kk) { aF[kk][0] = aN[kk][0]; aF[kk][1] = aN[kk][1]; }
    }
  }

  // epilogue: C layout col=lane&15, row=(lane>>4)*4+i (m89-verified)
#pragma unroll
  for (int dt = 0; dt < 4; ++dt) {
    const int d = dt * 16 + l15;
#pragma unroll
    for (int i = 0; i < 4; ++i) {
      const int v = v0 + wave * 16 + lhi * 4 + i;
      if (v < NN) atomicAdd(&out[(size_t)v * DD + d], acc[dt][i]);
    }
  }
}

extern "C" void kernel_launch(void* const* d_in, const int* in_sizes, int n_in,
                              void* d_out, int out_size, void* d_ws, size_t ws_size,
                              hipStream_t stream) {
  const float* H    = (const float*)d_in[0];
  const float* A1   = (const float*)d_in[1];
  const float* A2   = (const float*)d_in[2];
  const float* A3   = (const float*)d_in[3];
  const float* W1   = (const float*)d_in[4];
  const float* W2   = (const float*)d_in[5];
  const float* W3   = (const float*)d_in[6];
  const float* bias = (const float*)d_in[7];
  float* out = (float*)d_out;
  unsigned short* mt = (unsigned short*)d_ws;  // M_T[3][64][KP] bf16 = 3.75 MB

  prep_kernel<<<dim3(KP / 128, 3), 256, 0, stream>>>(H, W1, W2, W3, mt);
  init_out_kernel<<<dim3((NN * DD + 255) / 256), 256, 0, stream>>>(bias, out);
  gcn_main<<<dim3((NN + BM - 1) / BM, SPLITS, 3), 256, 0, stream>>>(A1, A2, A3, mt, out);
}

// Round 5
// 310.112 us; speedup vs baseline: 1.0437x; 1.0437x over previous
//
#include <hip/hip_runtime.h>

// Problem constants
static constexpr int NN = 10000;   // nodes
static constexpr int DD = 64;      // in/out dim
static constexpr int KP = 10240;   // padded K for M_T
static constexpr int BK = 128;     // K per inner iter
static constexpr int SPLITS = 4;   // K-split factor (grid.y)
static constexpr int KC = KP / SPLITS;  // 2560 K per block
static constexpr int ITERS = KC / BK;   // 20 (even)
static constexpr int BM = 64;      // rows per block

typedef __attribute__((ext_vector_type(4))) float f32x4;
typedef __attribute__((ext_vector_type(8))) short s16x8;

__device__ __forceinline__ unsigned short f2bf(float f) {
  // fp32 -> bf16 round-to-nearest-even (bit trick; inputs finite)
  unsigned u = __float_as_uint(f);
  return (unsigned short)((u + 0x7fffu + ((u >> 16) & 1u)) >> 16);
}

// async global->LDS DMA, 16 B per lane: dest = ldsbase + lane*16 (wave-uniform base),
// src per-lane (pre-swizzled global addressing, m173 pattern). Counts 1 in vmcnt.
__device__ __forceinline__ void g2l16(const void* g, void* l) {
  __builtin_amdgcn_global_load_lds((const __attribute__((address_space(1))) unsigned int*)g,
                                   (__attribute__((address_space(3))) unsigned int*)l, 16, 0, 0);
}

// ---------- prep: M_T[r][d][k] = bf16( sum_j H[k][j] * W_r[d][j] ), zero-padded to KP ----------
__global__ void prep_kernel(const float* __restrict__ H,
                            const float* __restrict__ W1,
                            const float* __restrict__ W2,
                            const float* __restrict__ W3,
                            unsigned short* __restrict__ mt) {
  const int r = blockIdx.y;
  const float* W = (r == 0) ? W1 : (r == 1) ? W2 : W3;
  const int wave = threadIdx.x >> 6;
  const int lane = threadIdx.x & 63;   // lane == output dim d
  f32x4 wr[16];
#pragma unroll
  for (int i = 0; i < 16; ++i) wr[i] = *(const f32x4*)&W[lane * 64 + i * 4];
  unsigned short* orow = mt + ((size_t)r * 64 + lane) * KP;
  const int kbase = blockIdx.x * 128 + wave * 32;
  for (int i = 0; i < 32; ++i) {
    const int k = kbase + i;
    if (k < NN) {
      float s = 0.f;
#pragma unroll
      for (int j = 0; j < 16; ++j) {
        f32x4 h = *(const f32x4*)&H[(size_t)k * 64 + j * 4]; // wave-uniform addr -> broadcast
        s += h[0] * wr[j][0] + h[1] * wr[j][1] + h[2] * wr[j][2] + h[3] * wr[j][3];
      }
      orow[k] = f2bf(s);
    } else {
      orow[k] = 0;  // zero pad k in [10000,10240)
    }
  }
}

// ---------- init: out[v][d] = bias[d] ----------
__global__ void init_out_kernel(const float* __restrict__ bias, float* __restrict__ out) {
  const int i = blockIdx.x * 256 + threadIdx.x;
  if (i < NN * DD) out[i] = bias[i & 63];
}

// ---------- main: out += A_r[:, kchunk] @ M_r[kchunk, :]  (bf16 MFMA) ----------
// Forced software pipeline: A-loads issued via inline-asm global_load_dwordx4 into
// two explicit register banks (unroll-2), M staged via global_load_lds DMA (swizzled
// source). One counted s_waitcnt vmcnt(12) per iter (next tile's 8 A + 4 M stay in
// flight across raw s_barriers) -- no vmcnt(0) drain in the main loop.
__global__ __launch_bounds__(256, 4) void gcn_main(const float* __restrict__ A1,
                                                   const float* __restrict__ A2,
                                                   const float* __restrict__ A3,
                                                   const unsigned short* __restrict__ mt,
                                                   float* __restrict__ out) {
  // [buf][row][128 hw]; row = 256 B = 16 segs of 16 B. Stored seg for (row,g) is
  // g ^ (row & 15) -- realized by pre-swizzling the DMA source; LDS dest linear.
  __shared__ __align__(1024) unsigned short mlds[2][64][128];

  const int r = blockIdx.z;
  const int s = blockIdx.y;
  const float* A = (r == 0) ? A1 : (r == 1) ? A2 : A3;
  const unsigned short* mtr = mt + (size_t)r * 64 * KP;

  const int wave = threadIdx.x >> 6;
  const int lane = threadIdx.x & 63;
  const int l15 = lane & 15;
  const int lhi = lane >> 4;
  const int seg = lane & 15;   // 16-B segment this lane DMAs
  const int r16 = lane >> 4;   // row-within-4 this lane DMAs
  const int v0 = blockIdx.x * BM;
  const int k0 = s * KC;

  // A row this lane streams (clamped for tail block; garbage rows never stored)
  int vA = v0 + wave * 16 + l15;
  if (vA > NN - 1) vA = NN - 1;
  const float* arow = A + (size_t)vA * NN;

  f32x4 acc[4] = {{0.f,0.f,0.f,0.f},{0.f,0.f,0.f,0.f},{0.f,0.f,0.f,0.f},{0.f,0.f,0.f,0.f}};
  f32x4 R0[4][2], R1[4][2];   // two A-fragment register banks (no copies)

  // DMA one BK-tile of M into mlds[buf] (4 instrs/wave, counts 4 in vmcnt).
  auto stageM = [&](int t, int buf) {
    const int kb = k0 + t * BK;
#pragma unroll
    for (int j = 0; j < 4; ++j) {
      const int row16 = 4 * j + r16;                 // row & 15
      const int rowabs = wave * 16 + row16;
      const unsigned short* src = mtr + (size_t)rowabs * KP + kb + ((seg ^ row16) << 3);
      g2l16(src, &mlds[buf][wave * 16 + 4 * j][0]);
    }
  };

  // Issue 8 A-loads (exactly 8 vmem instrs in BOTH paths -> vmcnt bookkeeping holds).
  auto issueA = [&](f32x4 (&a)[4][2], int kb) {
    if (kb + BK <= NN) {               // block-uniform fast path: 1 base + imm offsets
      const float* p = arow + kb + lhi * 8;
      asm volatile(
        "global_load_dwordx4 %0, %8, off\n\t"
        "global_load_dwordx4 %1, %8, off offset:16\n\t"
        "global_load_dwordx4 %2, %8, off offset:128\n\t"
        "global_load_dwordx4 %3, %8, off offset:144\n\t"
        "global_load_dwordx4 %4, %8, off offset:256\n\t"
        "global_load_dwordx4 %5, %8, off offset:272\n\t"
        "global_load_dwordx4 %6, %8, off offset:384\n\t"
        "global_load_dwordx4 %7, %8, off offset:400"
        : "=&v"(a[0][0]), "=&v"(a[0][1]), "=&v"(a[1][0]), "=&v"(a[1][1]),
          "=&v"(a[2][0]), "=&v"(a[2][1]), "=&v"(a[3][0]), "=&v"(a[3][1])
        : "v"(p));
    } else {                           // tail: per-load clamped addresses (stay in-bounds)
      const int kf0 = kb + lhi * 8;
      const float* q0 = arow + ((kf0       < NN) ? kf0       : 0);
      const float* q1 = arow + ((kf0 + 4   < NN) ? kf0 + 4   : 0);
      const float* q2 = arow + ((kf0 + 32  < NN) ? kf0 + 32  : 0);
      const float* q3 = arow + ((kf0 + 36  < NN) ? kf0 + 36  : 0);
      const float* q4 = arow + ((kf0 + 64  < NN) ? kf0 + 64  : 0);
      const float* q5 = arow + ((kf0 + 68  < NN) ? kf0 + 68  : 0);
      const float* q6 = arow + ((kf0 + 96  < NN) ? kf0 + 96  : 0);
      const float* q7 = arow + ((kf0 + 100 < NN) ? kf0 + 100 : 0);
      asm volatile(
        "global_load_dwordx4 %0, %8, off\n\t"
        "global_load_dwordx4 %1, %9, off\n\t"
        "global_load_dwordx4 %2, %10, off\n\t"
        "global_load_dwordx4 %3, %11, off\n\t"
        "global_load_dwordx4 %4, %12, off\n\t"
        "global_load_dwordx4 %5, %13, off\n\t"
        "global_load_dwordx4 %6, %14, off\n\t"
        "global_load_dwordx4 %7, %15, off"
        : "=&v"(a[0][0]), "=&v"(a[0][1]), "=&v"(a[1][0]), "=&v"(a[1][1]),
          "=&v"(a[2][0]), "=&v"(a[2][1]), "=&v"(a[3][0]), "=&v"(a[3][1])
        : "v"(q0), "v"(q1), "v"(q2), "v"(q3), "v"(q4), "v"(q5), "v"(q6), "v"(q7));
    }
  };

  auto cvtA = [&](const f32x4& x, const f32x4& y) -> s16x8 {
    s16x8 v;
    v[0] = (short)f2bf(x[0]); v[1] = (short)f2bf(x[1]);
    v[2] = (short)f2bf(x[2]); v[3] = (short)f2bf(x[3]);
    v[4] = (short)f2bf(y[0]); v[5] = (short)f2bf(y[1]);
    v[6] = (short)f2bf(y[2]); v[7] = (short)f2bf(y[3]);
    return v;
  };

  auto body = [&](int t, f32x4 (&cur)[4][2], f32x4 (&nxt)[4][2]) {
    const int tn = (t + 1 < ITERS) ? t + 1 : ITERS - 1;   // clamped prefetch keeps count=12
    issueA(nxt, k0 + tn * BK);          // 8 vmem
    stageM(tn, (t + 1) & 1);            // 4 vmem (buf safe: last read of it ended pre-barrier)
    __builtin_amdgcn_sched_barrier(0);  // pin issue order above the wait
    asm volatile("s_waitcnt vmcnt(12)");// completes tile t's 8 A + 4 M; leaves t+1 in flight
    __builtin_amdgcn_sched_barrier(0);  // rule #18: nothing below may hoist above the wait
    __builtin_amdgcn_s_barrier();       // all waves' M(t) DMA done -> buf(t) readable
    const int kb = k0 + t * BK;
    const int buf = t & 1;
    if (kb + BK > NN) {                 // uniform tail: zero OOB-k fragments
      const f32x4 z = {0.f, 0.f, 0.f, 0.f};
#pragma unroll
      for (int kk = 0; kk < 4; ++kk) {
        const int kf = kb + kk * 32 + lhi * 8;
        cur[kk][0] = (kf     >= NN) ? z : cur[kk][0];
        cur[kk][1] = (kf + 4 >= NN) ? z : cur[kk][1];
      }
    }
#pragma unroll
    for (int kk = 0; kk < 4; ++kk) {
      s16x8 a = cvtA(cur[kk][0], cur[kk][1]);
#pragma unroll
      for (int dt = 0; dt < 4; ++dt) {
        const int g = kk * 4 + lhi;
        s16x8 b = *(const s16x8*)&mlds[buf][dt * 16 + l15][((g ^ l15) & 15) * 8];
        acc[dt] = __builtin_amdgcn_mfma_f32_16x16x32_bf16(a, b, acc[dt], 0, 0, 0);
      }
    }
    __builtin_amdgcn_sched_barrier(0);
    __builtin_amdgcn_s_barrier();       // all reads of buf(t) done before it's re-DMAed
  };

  // prologue: tile 0 in flight (12 outstanding)
  issueA(R0, k0);
  stageM(0, 0);

  for (int t = 0; t < ITERS; t += 2) {  // ITERS even
    body(t, R0, R1);
    body(t + 1, R1, R0);
  }

  asm volatile("s_waitcnt vmcnt(0)");   // drain trailing clamped prefetch before exit

  // epilogue: C layout col=lane&15, row=(lane>>4)*4+i (m89-verified)
#pragma unroll
  for (int dt = 0; dt < 4; ++dt) {
    const int d = dt * 16 + l15;
#pragma unroll
    for (int i = 0; i < 4; ++i) {
      const int v = v0 + wave * 16 + lhi * 4 + i;
      if (v < NN) atomicAdd(&out[(size_t)v * DD + d], acc[dt][i]);
    }
  }
}

extern "C" void kernel_launch(void* const* d_in, const int* in_sizes, int n_in,
                              void* d_out, int out_size, void* d_ws, size_t ws_size,
                              hipStream_t stream) {
  const float* H    = (const float*)d_in[0];
  const float* A1   = (const float*)d_in[1];
  const float* A2   = (const float*)d_in[2];
  const float* A3   = (const float*)d_in[3];
  const float* W1   = (const float*)d_in[4];
  const float* W2   = (const float*)d_in[5];
  const float* W3   = (const float*)d_in[6];
  const float* bias = (const float*)d_in[7];
  float* out = (float*)d_out;
  unsigned short* mt = (unsigned short*)d_ws;  // M_T[3][64][KP] bf16 = 3.75 MB

  prep_kernel<<<dim3(KP / 128, 3), 256, 0, stream>>>(H, W1, W2, W3, mt);
  init_out_kernel<<<dim3((NN * DD + 255) / 256), 256, 0, stream>>>(bias, out);
  gcn_main<<<dim3((NN + BM - 1) / BM, SPLITS, 3), 256, 0, stream>>>(A1, A2, A3, mt, out);
}

// Round 6
// 293.279 us; speedup vs baseline: 1.1036x; 1.0574x over previous
//
#include <hip/hip_runtime.h>

// Problem constants
static constexpr int NN = 10000;   // nodes
static constexpr int DD = 64;      // in/out dim
static constexpr int KP = 10240;   // padded K for M_T
static constexpr int BK = 128;     // K per inner iter
static constexpr int SPLITS = 4;   // K-split factor (grid.y)
static constexpr int KC = KP / SPLITS;  // 2560 K per block
static constexpr int ITERS = KC / BK;   // 20
static constexpr int BM = 64;      // rows per block

typedef __attribute__((ext_vector_type(4))) float f32x4;
typedef __attribute__((ext_vector_type(8))) short s16x8;
typedef __attribute__((ext_vector_type(4))) unsigned short u16x4;

__device__ __forceinline__ unsigned short f2bf(float f) {
  // fp32 -> bf16 round-to-nearest-even (bit trick; inputs finite)
  unsigned u = __float_as_uint(f);
  return (unsigned short)((u + 0x7fffu + ((u >> 16) & 1u)) >> 16);
}

// async global->LDS DMA, 16 B per lane: dest = ldsbase + lane*16 (wave-uniform base),
// src per-lane (pre-swizzled global addressing, m173 pattern). Counts 1 in vmcnt.
__device__ __forceinline__ void g2l16(const void* g, void* l) {
  __builtin_amdgcn_global_load_lds((const __attribute__((address_space(1))) unsigned int*)g,
                                   (__attribute__((address_space(3))) unsigned int*)l, 16, 0, 0);
}

// ---------- prep: M_T[r][d][k] = bf16( sum_j H[k][j] * W_r[d][j] ), zero-padded to KP ----------
__global__ void prep_kernel(const float* __restrict__ H,
                            const float* __restrict__ W1,
                            const float* __restrict__ W2,
                            const float* __restrict__ W3,
                            unsigned short* __restrict__ mt) {
  const int r = blockIdx.y;
  const float* W = (r == 0) ? W1 : (r == 1) ? W2 : W3;
  const int wave = threadIdx.x >> 6;
  const int lane = threadIdx.x & 63;   // lane == output dim d
  f32x4 wr[16];
#pragma unroll
  for (int i = 0; i < 16; ++i) wr[i] = *(const f32x4*)&W[lane * 64 + i * 4];
  unsigned short* orow = mt + ((size_t)r * 64 + lane) * KP;
  const int kbase = blockIdx.x * 128 + wave * 32;
  for (int i = 0; i < 32; ++i) {
    const int k = kbase + i;
    if (k < NN) {
      float s = 0.f;
#pragma unroll
      for (int j = 0; j < 16; ++j) {
        f32x4 h = *(const f32x4*)&H[(size_t)k * 64 + j * 4]; // wave-uniform addr -> broadcast
        s += h[0] * wr[j][0] + h[1] * wr[j][1] + h[2] * wr[j][2] + h[3] * wr[j][3];
      }
      orow[k] = f2bf(s);
    } else {
      orow[k] = 0;  // zero pad k in [10000,10240)
    }
  }
}

// ---------- init: out[v][d] = bias[d] ----------
__global__ void init_out_kernel(const float* __restrict__ bias, float* __restrict__ out) {
  const int i = blockIdx.x * 256 + threadIdx.x;
  if (i < NN * DD) out[i] = bias[i & 63];
}

// ---------- main: out += A_r[:, kchunk] @ M_r[kchunk, :]  (bf16 MFMA) ----------
// A loaded as CONTIGUOUS 512B-per-row bursts (DRAM-page friendly) -> reg cvt to bf16
// -> wave-private swizzled LDS tile -> ds_read_b128 MFMA frags. M via global_load_lds
// DMA (swizzled source). Counted vmcnt pipeline, one barrier pair per iter.
__global__ __launch_bounds__(256, 2) void gcn_main(const float* __restrict__ A1,
                                                   const float* __restrict__ A2,
                                                   const float* __restrict__ A3,
                                                   const unsigned short* __restrict__ mt,
                                                   float* __restrict__ out) {
  // Both tiles: [buf][row][128 hw]; row = 256 B = 16 segs of 16 B; element (row, seg)
  // stored at seg ^ (row & 15)  (A: applied at ds_write; M: via pre-swizzled DMA source).
  __shared__ __align__(1024) unsigned short mldsM[2][64][128];
  __shared__ __align__(1024) unsigned short mldsA[2][64][128];

  const int r = blockIdx.z;
  const int s = blockIdx.y;
  const float* A = (r == 0) ? A1 : (r == 1) ? A2 : A3;
  const unsigned short* mtr = mt + (size_t)r * 64 * KP;

  const int wave = threadIdx.x >> 6;
  const int lane = threadIdx.x & 63;
  const int l15 = lane & 15;
  const int lhi = lane >> 4;
  const int l31 = lane & 31;
  const int lh5 = lane >> 5;
  const int v0 = blockIdx.x * BM;
  const int k0 = s * KC;

  // ---- hoisted A addressing: instr j covers rows {16w+2j, 16w+2j+1}, 512 B each ----
  const float* rowPtr[8];
  int wOff[8];
#pragma unroll
  for (int j = 0; j < 8; ++j) {
    const int rloc = wave * 16 + 2 * j + lh5;          // local row 0..63
    int vr = v0 + rloc; if (vr > NN - 1) vr = NN - 1;  // clamp OOB rows (results discarded)
    rowPtr[j] = A + (size_t)vr * NN;
    // ds_write_b64 dest: lane l31 -> seg (l31>>1), half (lane&1); seg XOR row&15
    wOff[j] = rloc * 256 + (((l31 >> 1) ^ (rloc & 15)) * 16) + (lane & 1) * 8;
  }
  int rOffA[4], rOffM[4][4];
#pragma unroll
  for (int kk = 0; kk < 4; ++kk) {
    rOffA[kk] = (wave * 16 + l15) * 256 + (((kk * 4 + lhi) ^ l15) * 16);
#pragma unroll
    for (int dt = 0; dt < 4; ++dt)
      rOffM[kk][dt] = (dt * 16 + l15) * 256 + (((kk * 4 + lhi) ^ l15) * 16);
  }

  f32x4 acc[4] = {{0.f,0.f,0.f,0.f},{0.f,0.f,0.f,0.f},{0.f,0.f,0.f,0.f},{0.f,0.f,0.f,0.f}};
  f32x4 ar[8];

  // DMA one BK-tile of M into mldsM[buf] (4 instrs/wave; vmcnt +4).
  auto stageM = [&](int t, int buf) {
    const int kb = k0 + t * BK;
#pragma unroll
    for (int j = 0; j < 4; ++j) {
      const int row16 = 4 * j + (lane >> 4);           // row & 15
      const int rowabs = wave * 16 + row16;
      const unsigned short* src = mtr + (size_t)rowabs * KP + kb + (((lane & 15) ^ row16) << 3);
      g2l16(src, &mldsM[buf][wave * 16 + 4 * j][0]);
    }
  };

  // Issue 8 contiguous A loads (each: 2 rows x 512 B). Clamped k keeps all in-bounds;
  // clamped lanes are zeroed at cvt. Always exactly 8 vmem instrs.
  auto issueA = [&](int kb) {
    int koff = kb + l31 * 4;
    if (koff > NN - 4) koff = NN - 4;
    const float* p0 = rowPtr[0] + koff; const float* p1 = rowPtr[1] + koff;
    const float* p2 = rowPtr[2] + koff; const float* p3 = rowPtr[3] + koff;
    const float* p4 = rowPtr[4] + koff; const float* p5 = rowPtr[5] + koff;
    const float* p6 = rowPtr[6] + koff; const float* p7 = rowPtr[7] + koff;
    asm volatile(
      "global_load_dwordx4 %0, %8, off\n\t"
      "global_load_dwordx4 %1, %9, off\n\t"
      "global_load_dwordx4 %2, %10, off\n\t"
      "global_load_dwordx4 %3, %11, off\n\t"
      "global_load_dwordx4 %4, %12, off\n\t"
      "global_load_dwordx4 %5, %13, off\n\t"
      "global_load_dwordx4 %6, %14, off\n\t"
      "global_load_dwordx4 %7, %15, off"
      : "=&v"(ar[0]), "=&v"(ar[1]), "=&v"(ar[2]), "=&v"(ar[3]),
        "=&v"(ar[4]), "=&v"(ar[5]), "=&v"(ar[6]), "=&v"(ar[7])
      : "v"(p0), "v"(p1), "v"(p2), "v"(p3), "v"(p4), "v"(p5), "v"(p6), "v"(p7));
  };

  // cvt fp32->bf16 and store 8 B/lane into mldsA[buf] (swizzled, wave-private quadrant).
  auto cvtWrite = [&](int buf, int kb) {
    if (kb + BK > NN) {                  // tail: zero OOB-k lanes (uniform outer branch)
      if (kb + l31 * 4 > NN - 4) {
#pragma unroll
        for (int j = 0; j < 8; ++j) ar[j] = (f32x4){0.f, 0.f, 0.f, 0.f};
      }
    }
    char* base = (char*)&mldsA[buf][0][0];
#pragma unroll
    for (int j = 0; j < 8; ++j) {
      u16x4 c;
      c[0] = f2bf(ar[j][0]); c[1] = f2bf(ar[j][1]);
      c[2] = f2bf(ar[j][2]); c[3] = f2bf(ar[j][3]);
      *(u16x4*)(base + wOff[j]) = c;
    }
  };

  // ---- prologue: tile 0 ----
  issueA(k0);
  __builtin_amdgcn_sched_barrier(0);
  stageM(0, 0);
  __builtin_amdgcn_sched_barrier(0);
  asm volatile("s_waitcnt vmcnt(4)");
  __builtin_amdgcn_sched_barrier(0);
  cvtWrite(0, k0);
  __builtin_amdgcn_sched_barrier(0);
  asm volatile("s_waitcnt vmcnt(0)");
  __builtin_amdgcn_sched_barrier(0);
  __builtin_amdgcn_s_barrier();

  for (int t = 0; t < ITERS; ++t) {
    const int buf = t & 1;
    const int tn = (t + 1 < ITERS) ? t + 1 : t;   // last iter: dup (unread), keeps counts uniform
    const int kbn = k0 + tn * BK;
    issueA(kbn);                        // 8 vmem (HBM, contiguous bursts)
    __builtin_amdgcn_sched_barrier(0);
    stageM(tn, buf ^ 1);                // 4 vmem (L2-hot DMA)
    __builtin_amdgcn_sched_barrier(0);
    // MFMA on tile t from LDS[buf]
    {
      const char* aBase = (const char*)&mldsA[buf][0][0];
      const char* mBase = (const char*)&mldsM[buf][0][0];
#pragma unroll
      for (int kk = 0; kk < 4; ++kk) {
        s16x8 a = *(const s16x8*)(aBase + rOffA[kk]);
#pragma unroll
        for (int dt = 0; dt < 4; ++dt) {
          s16x8 b = *(const s16x8*)(mBase + rOffM[kk][dt]);
          acc[dt] = __builtin_amdgcn_mfma_f32_16x16x32_bf16(a, b, acc[dt], 0, 0, 0);
        }
      }
    }
    __builtin_amdgcn_sched_barrier(0);
    asm volatile("s_waitcnt vmcnt(4)"); // A(tn) regs landed (issued before MFMA block)
    __builtin_amdgcn_sched_barrier(0);  // rule #18: pin cvt below the wait
    cvtWrite(buf ^ 1, kbn);
    __builtin_amdgcn_sched_barrier(0);
    asm volatile("s_waitcnt vmcnt(0)"); // M(tn) DMA done (issued ~600 cyc ago, L2-hot)
    __builtin_amdgcn_sched_barrier(0);
    __builtin_amdgcn_s_barrier();
  }

  // epilogue: C layout col=lane&15, row=(lane>>4)*4+i (m89-verified)
#pragma unroll
  for (int dt = 0; dt < 4; ++dt) {
    const int d = dt * 16 + l15;
#pragma unroll
    for (int i = 0; i < 4; ++i) {
      const int v = v0 + wave * 16 + lhi * 4 + i;
      if (v < NN) atomicAdd(&out[(size_t)v * DD + d], acc[dt][i]);
    }
  }
}

extern "C" void kernel_launch(void* const* d_in, const int* in_sizes, int n_in,
                              void* d_out, int out_size, void* d_ws, size_t ws_size,
                              hipStream_t stream) {
  const float* H    = (const float*)d_in[0];
  const float* A1   = (const float*)d_in[1];
  const float* A2   = (const float*)d_in[2];
  const float* A3   = (const float*)d_in[3];
  const float* W1   = (const float*)d_in[4];
  const float* W2   = (const float*)d_in[5];
  const float* W3   = (const float*)d_in[6];
  const float* bias = (const float*)d_in[7];
  float* out = (float*)d_out;
  unsigned short* mt = (unsigned short*)d_ws;  // M_T[3][64][KP] bf16 = 3.75 MB

  prep_kernel<<<dim3(KP / 128, 3), 256, 0, stream>>>(H, W1, W2, W3, mt);
  init_out_kernel<<<dim3((NN * DD + 255) / 256), 256, 0, stream>>>(bias, out);
  gcn_main<<<dim3((NN + BM - 1) / BM, SPLITS, 3), 256, 0, stream>>>(A1, A2, A3, mt, out);
}